// Round 10
// baseline (362.548 us; speedup 1.0000x reference)
//
#include <hip/hip_runtime.h>
#include <hip/hip_bf16.h>

#define NN 50000
#define NE 800000
#define FIN0 128
#define HID 60
#define CAT 180
#define NCLS 7
#define BN_EPS 1e-5f
#define NBUCK 196      // ceil(NN/256)
#define BCAP 5120      // max edges per 256-node bucket (mean 4096, sigma 64)
#define STG 96         // staged edge-index cap per node (P(deg>96) ~ 0)

typedef unsigned int uint;
typedef unsigned short ushort;
typedef __attribute__((ext_vector_type(8))) short short8;
typedef __attribute__((ext_vector_type(4))) float f32x4;

__device__ __forceinline__ ushort f2bf(float f) {
    uint u = __float_as_uint(f);
    u += 0x7FFFu + ((u >> 16) & 1u);
    return (ushort)(u >> 16);
}
__device__ __forceinline__ float bf_lo(uint v) { return __uint_as_float(v << 16); }
__device__ __forceinline__ float bf_hi(uint v) { return __uint_as_float(v & 0xFFFF0000u); }
__device__ __forceinline__ float bf2f(ushort u) { return __uint_as_float(((uint)u) << 16); }

// ---------------- weight pack (moved first; also inits gcur + zeroes gsumAll)
__global__ void k_wpack_all(
        const float* __restrict__ w00, const float* __restrict__ w01, const float* __restrict__ w02,
        const float* __restrict__ w10, const float* __restrict__ w11, const float* __restrict__ w12,
        const float* __restrict__ w20, const float* __restrict__ w21, const float* __restrict__ w22,
        ushort* __restrict__ WP0, ushort* __restrict__ WP1, ushort* __restrict__ WP2,
        int* __restrict__ gcur, float* __restrict__ gsumAll) {
    int l = blockIdx.z, p = blockIdx.y;
    int kt = blockIdx.x >> 2, ct = blockIdx.x & 3;
    int lane = threadIdx.x;  // 0..63
    // side duties (one block each)
    if (l == 0 && p == 0 && blockIdx.x == 0) {
        for (int i = lane; i < NBUCK; i += 64) gcur[i] = i * BCAP;
    }
    if (l == 0 && p == 1 && blockIdx.x == 0) {
        for (int i = lane; i < 3 * 2 * CAT; i += 64) gsumAll[i] = 0.f;
    }
    int KT = (l == 0) ? 4 : 6;
    if (kt >= KT) return;
    const float* W;
    if (l == 0) W = (p == 0) ? w00 : ((p == 1) ? w01 : w02);
    else if (l == 1) W = (p == 0) ? w10 : ((p == 1) ? w11 : w12);
    else W = (p == 0) ? w20 : ((p == 1) ? w21 : w22);
    ushort* WP = (l == 0) ? WP0 : ((l == 1) ? WP1 : WP2);
    int k0 = kt * 32 + (lane >> 4) * 8;
    int c = ct * 16 + (lane & 15);
    ushort* dst = WP + (((size_t)(p * KT + kt) * 4 + ct) << 9) + (lane << 3);
    ushort o[8];
#pragma unroll
    for (int j = 0; j < 8; ++j) {
        int kl = k0 + j;
        float v = 0.f;
        if (c < 60) {
            if (l == 0) {
                if (kl < FIN0) v = W[(size_t)kl * 60 + c];
            } else {
                int rgn = kl >> 6, cc = kl & 63;
                if (cc < 60) v = W[(size_t)(rgn * 60 + cc) * 60 + c];
            }
        }
        o[j] = f2bf(v);
    }
    *(ushort4*)dst = make_ushort4(o[0], o[1], o[2], o[3]);
    *(ushort4*)(dst + 4) = make_ushort4(o[4], o[5], o[6], o[7]);
}

// ---------------- CSR build: bucketed, write-combined, 4B packed entries ----
// entry: bits 0-15 = src (N < 65536), bits 16-23 = dst & 255
__global__ __launch_bounds__(256) void k_bin(const int* __restrict__ src,
                                             const int* __restrict__ dst,
                                             int* __restrict__ gcur,
                                             uint* __restrict__ ebuf, int e) {
    __shared__ int cnt[NBUCK];
    __shared__ int base[NBUCK];
    int t = threadIdx.x;
    for (int c0 = blockIdx.x * 2048; c0 < e; c0 += gridDim.x * 2048) {
        if (t < NBUCK) cnt[t] = 0;
        __syncthreads();
        uint pe[8]; int rk[8], bk[8], ok[8];
#pragma unroll
        for (int j = 0; j < 8; ++j) {
            int i = c0 + j * 256 + t;
            ok[j] = i < e;
            if (ok[j]) {
                int sv = src[i], dv = dst[i];
                pe[j] = (uint)(sv & 0xFFFF) | ((uint)(dv & 255) << 16);
                bk[j] = dv >> 8;
                rk[j] = atomicAdd(&cnt[bk[j]], 1);
            }
        }
        __syncthreads();
        if (t < NBUCK && cnt[t] > 0) base[t] = atomicAdd(&gcur[t], cnt[t]);
        __syncthreads();
#pragma unroll
        for (int j = 0; j < 8; ++j) {
            if (ok[j]) ebuf[base[bk[j]] + rk[j]] = pe[j];
        }
        __syncthreads();
    }
}

// one block per bucket: inline global prefix scan (196 counts), then exact CSR
__global__ __launch_bounds__(256) void k_bucket_csr(
        const int* __restrict__ gcur, const uint* __restrict__ ebuf,
        int* __restrict__ row_ptr, float* __restrict__ dinv,
        ushort* __restrict__ ssrc, int n) {
    __shared__ int sc[256];
    __shared__ int ncnt[256];
    __shared__ int loff[256];
    int b = blockIdx.x, t = threadIdx.x;
    int cbt = (t < NBUCK) ? (gcur[t] - t * BCAP) : 0;
    sc[t] = cbt;
    __syncthreads();
    for (int off = 1; off < 256; off <<= 1) {
        int v = (t >= off) ? sc[t - off] : 0;
        __syncthreads();
        sc[t] += v;
        __syncthreads();
    }
    int gbase = (b == 0) ? 0 : sc[b - 1];
    int cnt = sc[b] - gbase;
    if (b == 0 && t == 0) row_ptr[NN] = NE;
    const uint* ee = ebuf + (size_t)b * BCAP;
    ncnt[t] = 0;
    __syncthreads();
    for (int i = t; i < cnt; i += 256) atomicAdd(&ncnt[(ee[i] >> 16) & 255], 1);
    __syncthreads();
    int c = ncnt[t];
    loff[t] = c;
    __syncthreads();
    for (int off = 1; off < 256; off <<= 1) {
        int v = (t >= off) ? loff[t - off] : 0;
        __syncthreads();
        loff[t] += v;
        __syncthreads();
    }
    int excl = loff[t] - c;
    int node = b * 256 + t;
    if (node < n) {
        row_ptr[node] = gbase + excl;
        dinv[node] = rsqrtf((float)(c + 1));  // +1 self loop
    }
    __syncthreads();
    ncnt[t] = excl;  // reuse as cursor
    __syncthreads();
    for (int i = t; i < cnt; i += 256) {
        uint pe = ee[i];
        int pos = atomicAdd(&ncnt[(pe >> 16) & 255], 1);
        ssrc[gbase + pos] = (ushort)(pe & 0xFFFF);
    }
}

// ---------------- MFMA GEMM, 3 powers per block.
template <int KT, int MODE>
__global__ __launch_bounds__(256) void k_gemm_mfma(
        const float* __restrict__ Xf,
        const ushort* __restrict__ B0q, const ushort* __restrict__ B1q,
        const ushort* __restrict__ B2q,
        const float* __restrict__ gsum, const float* __restrict__ gsum2,
        const float* __restrict__ bng, const float* __restrict__ bnb,
        const ushort* __restrict__ WP,
        const float* __restrict__ b0, const float* __restrict__ dinv,
        ushort* __restrict__ Y0, ushort* __restrict__ Y12, int n) {
    __shared__ float ssc[200], ssh[200];
    const int t = threadIdx.x;
    if (MODE == 1) {
        if (t < 192) {
            int rgn = t >> 6, cc = t & 63;
            float sc = 0.f, sh = 0.f;
            if (cc < 60) {
                int c = rgn * 60 + cc;
                float mu = gsum[c] / (float)n;
                float var = gsum2[c] / (float)n - mu * mu;
                sc = rsqrtf(var + BN_EPS) * bng[c];
                sh = bnb[c] - mu * sc;
            }
            ssc[t] = sc; ssh[t] = sh;
        }
        __syncthreads();
    }
    const int wv = t >> 6;
    const int lane = t & 63;
    const int l15 = lane & 15;
    const int lhi = lane >> 4;
    const int nb = blockIdx.x * 64 + wv * 16;

    f32x4 acc[3][4];
#pragma unroll
    for (int p = 0; p < 3; ++p)
#pragma unroll
        for (int ct = 0; ct < 4; ++ct) acc[p][ct] = (f32x4){0.f, 0.f, 0.f, 0.f};

    const int arow = nb + l15;
    const int arowc = (arow < n) ? arow : 0;
    const ushort* wpL = WP + (lane << 3);

#pragma unroll
    for (int kt = 0; kt < KT; ++kt) {
        short8 a;
        if (MODE == 0) {
            const float* xr = Xf + (size_t)arowc * (KT * 32) + kt * 32 + lhi * 8;
            float4 v0 = *(const float4*)xr;
            float4 v1 = *(const float4*)(xr + 4);
            a[0] = (short)f2bf(v0.x); a[1] = (short)f2bf(v0.y);
            a[2] = (short)f2bf(v0.z); a[3] = (short)f2bf(v0.w);
            a[4] = (short)f2bf(v1.x); a[5] = (short)f2bf(v1.y);
            a[6] = (short)f2bf(v1.z); a[7] = (short)f2bf(v1.w);
        } else {
            const ushort* base = (kt < 2) ? B0q : ((kt < 4) ? B1q : B2q);
            const ushort* ar = base + (size_t)arowc * 64 + (kt & 1) * 32 + lhi * 8;
            uint4 raw = *(const uint4*)ar;
            int kb = kt * 32 + lhi * 8;
            float4 sc0 = *(const float4*)&ssc[kb];
            float4 sc1 = *(const float4*)&ssc[kb + 4];
            float4 sh0 = *(const float4*)&ssh[kb];
            float4 sh1 = *(const float4*)&ssh[kb + 4];
            a[0] = (short)f2bf(bf_lo(raw.x) * sc0.x + sh0.x);
            a[1] = (short)f2bf(bf_hi(raw.x) * sc0.y + sh0.y);
            a[2] = (short)f2bf(bf_lo(raw.y) * sc0.z + sh0.z);
            a[3] = (short)f2bf(bf_hi(raw.y) * sc0.w + sh0.w);
            a[4] = (short)f2bf(bf_lo(raw.z) * sc1.x + sh1.x);
            a[5] = (short)f2bf(bf_hi(raw.z) * sc1.y + sh1.y);
            a[6] = (short)f2bf(bf_lo(raw.w) * sc1.z + sh1.z);
            a[7] = (short)f2bf(bf_hi(raw.w) * sc1.w + sh1.w);
        }
#pragma unroll
        for (int p = 0; p < 3; ++p)
#pragma unroll
            for (int ct = 0; ct < 4; ++ct) {
                short8 b = *(const short8*)(wpL + (((size_t)(p * KT + kt) * 4 + ct) << 9));
                acc[p][ct] = __builtin_amdgcn_mfma_f32_16x16x32_bf16(a, b, acc[p][ct], 0, 0, 0);
            }
    }

    // C/D layout: col = lane&15, row = (lane>>4)*4 + reg
    float dv[4];
#pragma unroll
    for (int j = 0; j < 4; ++j) {
        int node = nb + lhi * 4 + j;
        dv[j] = (node < n) ? dinv[node] : 0.f;
    }
#pragma unroll
    for (int ct = 0; ct < 4; ++ct) {
        int col = ct * 16 + l15;
        if (col >= 60) continue;
        float bias = b0[col];
#pragma unroll
        for (int j = 0; j < 4; ++j) {
            int node = nb + lhi * 4 + j;
            if (node >= n) continue;
            Y0[(size_t)node * 64 + col] = f2bf(acc[0][ct][j] + bias);
            uint pk = ((uint)f2bf(dv[j] * acc[2][ct][j]) << 16) |
                      (uint)f2bf(dv[j] * acc[1][ct][j]);
            *(uint*)(Y12 + (size_t)node * 128 + 2 * col) = pk;
        }
    }
}

// ---------------- propA: 2 nodes/wave, double-buffered 16-deep gathers
// lane hl<30 owns cols 2hl,2hl+1 (uint2 = both channels of both cols)
__global__ __launch_bounds__(256) void k_propA(
        const ushort* __restrict__ Y12, ushort* __restrict__ Z1, ushort* __restrict__ ZQ,
        const float* __restrict__ b1,
        const float* __restrict__ dinv, const int* __restrict__ rp,
        const ushort* __restrict__ es, int n) {
    __shared__ ushort sidx[8][STG];
    int sub = threadIdx.x >> 5;      // 0..7 node slot
    int hl = threadIdx.x & 31;       // half-wave lane
    int node = blockIdx.x * 8 + sub;
    if (node >= n) return;
    int e0 = rp[node], e1 = rp[node + 1];
    int deg = e1 - e0;
    int stg = (deg < STG) ? deg : STG;
    for (int i = hl; i < stg; i += 32) sidx[sub][i] = es[e0 + i];
    if (hl >= 30) return;
    uint2 sv = *(const uint2*)(Y12 + (size_t)node * 128 + hl * 4);
    float a1x = bf_lo(sv.x), a2x = bf_hi(sv.x);
    float a1y = bf_lo(sv.y), a2y = bf_hi(sv.y);
#define LOADA(buf, base)                                                      \
    _Pragma("unroll") for (int j = 0; j < 16; ++j) {                          \
        int s = sidx[sub][(base) + j];                                        \
        buf[j] = *(const uint2*)(Y12 + (size_t)s * 128 + hl * 4);             \
    }
#define ACCA(buf)                                                             \
    _Pragma("unroll") for (int j = 0; j < 16; ++j) {                          \
        a1x += bf_lo(buf[j].x); a2x += bf_hi(buf[j].x);                       \
        a1y += bf_lo(buf[j].y); a2y += bf_hi(buf[j].y);                       \
    }
    int nfull = stg >> 4;
    uint2 va[16], vb[16];
    if (nfull > 0) LOADA(va, 0);
    for (int c = 0; c < nfull; ++c) {
        if (c & 1) {
            if (c + 1 < nfull) LOADA(va, (c + 1) * 16);
            ACCA(vb);
        } else {
            if (c + 1 < nfull) LOADA(vb, (c + 1) * 16);
            ACCA(va);
        }
    }
    int e = nfull * 16;
    for (; e + 3 < stg; e += 4) {
        uint2 v[4];
#pragma unroll
        for (int j = 0; j < 4; ++j) {
            int s = sidx[sub][e + j];
            v[j] = *(const uint2*)(Y12 + (size_t)s * 128 + hl * 4);
        }
#pragma unroll
        for (int j = 0; j < 4; ++j) {
            a1x += bf_lo(v[j].x); a2x += bf_hi(v[j].x);
            a1y += bf_lo(v[j].y); a2y += bf_hi(v[j].y);
        }
    }
    for (; e < stg; ++e) {
        uint2 v = *(const uint2*)(Y12 + (size_t)sidx[sub][e] * 128 + hl * 4);
        a1x += bf_lo(v.x); a2x += bf_hi(v.x);
        a1y += bf_lo(v.y); a2y += bf_hi(v.y);
    }
    for (int ee = e0 + stg; ee < e1; ++ee) {  // overflow tail (rare)
        uint2 v = *(const uint2*)(Y12 + (size_t)es[ee] * 128 + hl * 4);
        a1x += bf_lo(v.x); a2x += bf_hi(v.x);
        a1y += bf_lo(v.y); a2y += bf_hi(v.y);
    }
#undef LOADA
#undef ACCA
    float di = dinv[node];
    int c0 = 2 * hl;
    uint z1 = ((uint)f2bf(di * a1y + b1[c0 + 1]) << 16) | (uint)f2bf(di * a1x + b1[c0]);
    uint zq = ((uint)f2bf(di * di * a2y) << 16) | (uint)f2bf(di * di * a2x);
    *(uint*)(Z1 + (size_t)node * 64 + c0) = z1;
    *(uint*)(ZQ + (size_t)node * 64 + c0) = zq;
}

// ---------------- propB: 2 nodes/wave over ZQ (s64) -> Q2 (+b2)
__global__ __launch_bounds__(256) void k_propB(
        const ushort* __restrict__ ZQ, ushort* __restrict__ Q2,
        const float* __restrict__ b2,
        const float* __restrict__ dinv, const int* __restrict__ rp,
        const ushort* __restrict__ es, int n) {
    __shared__ ushort sidx[8][STG];
    int sub = threadIdx.x >> 5;
    int hl = threadIdx.x & 31;
    int node = blockIdx.x * 8 + sub;
    if (node >= n) return;
    int e0 = rp[node], e1 = rp[node + 1];
    int deg = e1 - e0;
    int stg = (deg < STG) ? deg : STG;
    for (int i = hl; i < stg; i += 32) sidx[sub][i] = es[e0 + i];
    if (hl >= 30) return;
    uint sv = *(const uint*)(ZQ + (size_t)node * 64 + 2 * hl);
    float ax = bf_lo(sv), ay = bf_hi(sv);
#define LOADB(buf, base)                                                      \
    _Pragma("unroll") for (int j = 0; j < 16; ++j) {                          \
        int s = sidx[sub][(base) + j];                                        \
        buf[j] = *(const uint*)(ZQ + (size_t)s * 64 + 2 * hl);                \
    }
#define ACCB(buf)                                                             \
    _Pragma("unroll") for (int j = 0; j < 16; ++j) {                          \
        ax += bf_lo(buf[j]); ay += bf_hi(buf[j]);                             \
    }
    int nfull = stg >> 4;
    uint va[16], vb[16];
    if (nfull > 0) LOADB(va, 0);
    for (int c = 0; c < nfull; ++c) {
        if (c & 1) {
            if (c + 1 < nfull) LOADB(va, (c + 1) * 16);
            ACCB(vb);
        } else {
            if (c + 1 < nfull) LOADB(vb, (c + 1) * 16);
            ACCB(va);
        }
    }
    int e = nfull * 16;
    for (; e + 3 < stg; e += 4) {
        uint v[4];
#pragma unroll
        for (int j = 0; j < 4; ++j) {
            int s = sidx[sub][e + j];
            v[j] = *(const uint*)(ZQ + (size_t)s * 64 + 2 * hl);
        }
#pragma unroll
        for (int j = 0; j < 4; ++j) { ax += bf_lo(v[j]); ay += bf_hi(v[j]); }
    }
    for (; e < stg; ++e) {
        uint v = *(const uint*)(ZQ + (size_t)sidx[sub][e] * 64 + 2 * hl);
        ax += bf_lo(v); ay += bf_hi(v);
    }
    for (int ee = e0 + stg; ee < e1; ++ee) {
        uint v = *(const uint*)(ZQ + (size_t)es[ee] * 64 + 2 * hl);
        ax += bf_lo(v); ay += bf_hi(v);
    }
#undef LOADB
#undef ACCB
    float di = dinv[node];
    int c0 = 2 * hl;
    uint q = ((uint)f2bf(di * ay + b2[c0 + 1]) << 16) | (uint)f2bf(di * ax + b2[c0]);
    *(uint*)(Q2 + (size_t)node * 64 + c0) = q;
}

// ---------------- BN stats: coalesced uint4 reads, shfl+LDS reduce
__global__ __launch_bounds__(256) void k_bnstats(
        const ushort* __restrict__ Y0, const ushort* __restrict__ Z1,
        const ushort* __restrict__ Q2,
        float* __restrict__ gsum, float* __restrict__ gsum2, int n) {
    int rgn = blockIdx.y;
    const ushort* __restrict__ src = (rgn == 0) ? Y0 : ((rgn == 1) ? Z1 : Q2);
    int t = threadIdx.x;
    int c8 = (t & 7) * 8;
    int rsub = t >> 3;
    float s1[8], s2[8];
#pragma unroll
    for (int j = 0; j < 8; ++j) { s1[j] = 0.f; s2[j] = 0.f; }
    for (int r = blockIdx.x * 32 + rsub; r < n; r += gridDim.x * 32) {
        uint4 v = *(const uint4*)(src + (size_t)r * 64 + c8);
        float f;
        f = bf_lo(v.x); s1[0] += f; s2[0] += f * f;
        f = bf_hi(v.x); s1[1] += f; s2[1] += f * f;
        f = bf_lo(v.y); s1[2] += f; s2[2] += f * f;
        f = bf_hi(v.y); s1[3] += f; s2[3] += f * f;
        f = bf_lo(v.z); s1[4] += f; s2[4] += f * f;
        f = bf_hi(v.z); s1[5] += f; s2[5] += f * f;
        f = bf_lo(v.w); s1[6] += f; s2[6] += f * f;
        f = bf_hi(v.w); s1[7] += f; s2[7] += f * f;
    }
#pragma unroll
    for (int m = 8; m < 64; m <<= 1) {
#pragma unroll
        for (int j = 0; j < 8; ++j) {
            s1[j] += __shfl_xor(s1[j], m);
            s2[j] += __shfl_xor(s2[j], m);
        }
    }
    __shared__ float ls1[4][64], ls2[4][64];
    int wv = t >> 6, lane = t & 63;
    if (lane < 8) {
#pragma unroll
        for (int j = 0; j < 8; ++j) {
            ls1[wv][lane * 8 + j] = s1[j];
            ls2[wv][lane * 8 + j] = s2[j];
        }
    }
    __syncthreads();
    if (t < 60) {
        float a1 = ls1[0][t] + ls1[1][t] + ls1[2][t] + ls1[3][t];
        float a2 = ls2[0][t] + ls2[1][t] + ls2[2][t] + ls2[3][t];
        atomicAdd(&gsum[rgn * 60 + t], a1);
        atomicAdd(&gsum2[rgn * 60 + t], a2);
    }
}

// ---------------- final linear with fused BN (layer 3): out = BN(h) @ w + b
__global__ __launch_bounds__(256) void k_final_fused(
        const ushort* __restrict__ Y0, const ushort* __restrict__ Z1,
        const ushort* __restrict__ Q2,
        const float* __restrict__ gsum, const float* __restrict__ gsum2,
        const float* __restrict__ g, const float* __restrict__ bb,
        const float* __restrict__ w, const float* __restrict__ wb,
        float* __restrict__ out, int n) {
    __shared__ float sw[CAT * NCLS];
    __shared__ float ssc[CAT], ssh[CAT];
    __shared__ float sb[NCLS];
    int t = threadIdx.x;
    for (int i = t; i < CAT * NCLS; i += 256) sw[i] = w[i];
    if (t < CAT) {
        float mu = gsum[t] / (float)n;
        float var = gsum2[t] / (float)n - mu * mu;
        float sc = rsqrtf(var + BN_EPS) * g[t];
        ssc[t] = sc;
        ssh[t] = bb[t] - mu * sc;
    }
    if (t < NCLS) sb[t] = wb[t];
    __syncthreads();
    int node = blockIdx.x * 256 + t;
    if (node >= n) return;
    float acc[NCLS];
#pragma unroll
    for (int j = 0; j < NCLS; ++j) acc[j] = sb[j];
    const ushort* bufs[3] = {Y0, Z1, Q2};
#pragma unroll
    for (int rgn = 0; rgn < 3; ++rgn) {
        const ushort* sp = bufs[rgn] + (size_t)node * 64;
        int cb = rgn * 60;
#pragma unroll 6
        for (int k2 = 0; k2 < 30; ++k2) {
            uint u = *(const uint*)(sp + 2 * k2);
            int c = cb + 2 * k2;
            float f0 = bf_lo(u) * ssc[c] + ssh[c];
            float f1 = bf_hi(u) * ssc[c + 1] + ssh[c + 1];
#pragma unroll
            for (int j = 0; j < NCLS; ++j)
                acc[j] += f0 * sw[c * NCLS + j] + f1 * sw[(c + 1) * NCLS + j];
        }
    }
#pragma unroll
    for (int j = 0; j < NCLS; ++j) out[(size_t)node * NCLS + j] = acc[j];
}

extern "C" void kernel_launch(void* const* d_in, const int* in_sizes, int n_in,
                              void* d_out, int out_size, void* d_ws, size_t ws_size,
                              hipStream_t stream) {
    const float* x = (const float*)d_in[0];
    const int* ei = (const int*)d_in[1];
    const int* esrc = ei;
    const int* edst = ei + NE;

    const float* c_w[3][3];
    const float* c_b[3][3];
    for (int p = 0; p < 3; ++p)
        for (int l = 0; l < 3; ++l) {
            c_w[l][p] = (const float*)d_in[2 + p * 6 + l * 2];
            c_b[l][p] = (const float*)d_in[3 + p * 6 + l * 2];
        }
    const float* bn_g[3] = {(const float*)d_in[20], (const float*)d_in[22], (const float*)d_in[24]};
    const float* bn_b[3] = {(const float*)d_in[21], (const float*)d_in[23], (const float*)d_in[25]};
    const float* lw = (const float*)d_in[26];
    const float* lb = (const float*)d_in[27];
    float* out = (float*)d_out;

    char* wp = (char*)d_ws;
    auto alloc = [&](size_t bytes) {
        char* p = wp;
        wp += (bytes + 255) & ~(size_t)255;
        return p;
    };
    int* gcur = (int*)alloc((size_t)NBUCK * 4);
    uint* ebuf = (uint*)alloc((size_t)NBUCK * BCAP * 4);
    int* row_ptr = (int*)alloc((size_t)(NN + 1) * 4);
    ushort* ssrc = (ushort*)alloc((size_t)NE * 2);
    float* dinv = (float*)alloc((size_t)NN * 4);
    float* gsumAll = (float*)alloc((size_t)3 * 2 * CAT * 4);  // [layer][sum|sum2]
    ushort* Y0 = (ushort*)alloc((size_t)NN * 64 * 2);
    ushort* Y12 = (ushort*)alloc((size_t)NN * 128 * 2);
    ushort* Z1 = (ushort*)alloc((size_t)NN * 64 * 2);
    ushort* ZQ = (ushort*)alloc((size_t)NN * 64 * 2);
    ushort* Q2 = (ushort*)alloc((size_t)NN * 64 * 2);
    ushort* WP1 = (ushort*)alloc((size_t)3 * 4 * 4 * 512 * 2);
    ushort* WP2 = (ushort*)alloc((size_t)3 * 6 * 4 * 512 * 2);
    ushort* WP3 = (ushort*)alloc((size_t)3 * 6 * 4 * 512 * 2);

    auto gs = [&](int l) { return gsumAll + (size_t)l * 2 * CAT; };
    auto gs2 = [&](int l) { return gsumAll + (size_t)l * 2 * CAT + CAT; };

    // ---- weight packs + gcur init + gsum zero (one launch) ----
    k_wpack_all<<<dim3(24, 3, 3), 64, 0, stream>>>(
        c_w[0][0], c_w[0][1], c_w[0][2],
        c_w[1][0], c_w[1][1], c_w[1][2],
        c_w[2][0], c_w[2][1], c_w[2][2],
        WP1, WP2, WP3, gcur, gsumAll);

    // ---- CSR build (write-combined bucketed sort) ----
    k_bin<<<391, 256, 0, stream>>>(esrc, edst, gcur, ebuf, NE);
    k_bucket_csr<<<NBUCK, 256, 0, stream>>>(gcur, ebuf, row_ptr, dinv, ssrc, NN);

    const int gemm_gx = (NN + 63) / 64;
    const int prop_gx = (NN + 7) / 8;

    for (int l = 0; l < 3; ++l) {
        if (l == 0) {
            k_gemm_mfma<4, 0><<<gemm_gx, 256, 0, stream>>>(
                x, nullptr, nullptr, nullptr, nullptr, nullptr, nullptr, nullptr,
                WP1, c_b[0][0], dinv, Y0, Y12, NN);
        } else {
            const ushort* WPl = (l == 1) ? WP2 : WP3;
            k_gemm_mfma<6, 1><<<gemm_gx, 256, 0, stream>>>(
                nullptr, Y0, Z1, Q2, gs(l - 1), gs2(l - 1), bn_g[l - 1], bn_b[l - 1],
                WPl, c_b[l][0], dinv, Y0, Y12, NN);
        }
        k_propA<<<prop_gx, 256, 0, stream>>>(Y12, Z1, ZQ, c_b[l][1], dinv, row_ptr, ssrc, NN);
        k_propB<<<prop_gx, 256, 0, stream>>>(ZQ, Q2, c_b[l][2], dinv, row_ptr, ssrc, NN);
        k_bnstats<<<dim3(256, 3), 256, 0, stream>>>(Y0, Z1, Q2, gs(l), gs2(l), NN);
    }

    k_final_fused<<<(NN + 255) / 256, 256, 0, stream>>>(
        Y0, Z1, Q2, gs(2), gs2(2), bn_g[2], bn_b[2], lw, lb, out, NN);
}

// Round 11
// 325.098 us; speedup vs baseline: 1.1152x; 1.1152x over previous
//
#include <hip/hip_runtime.h>
#include <hip/hip_bf16.h>

#define NN 50000
#define NE 800000
#define FIN0 128
#define HID 60
#define CAT 180
#define NCLS 7
#define BN_EPS 1e-5f
#define NBUCK 196      // ceil(NN/256)
#define BCAP 5120      // max edges per 256-node bucket (mean 4096, sigma 64)
#define STG 96         // staged edge-index cap per node (P(deg>96) ~ 0)

typedef unsigned int uint;
typedef unsigned short ushort;
typedef __attribute__((ext_vector_type(8))) short short8;
typedef __attribute__((ext_vector_type(4))) float f32x4;

__device__ __forceinline__ ushort f2bf(float f) {
    uint u = __float_as_uint(f);
    u += 0x7FFFu + ((u >> 16) & 1u);
    return (ushort)(u >> 16);
}
__device__ __forceinline__ float bf_lo(uint v) { return __uint_as_float(v << 16); }
__device__ __forceinline__ float bf_hi(uint v) { return __uint_as_float(v & 0xFFFF0000u); }
__device__ __forceinline__ float bf2f(ushort u) { return __uint_as_float(((uint)u) << 16); }

// ---------------- weight pack (also inits gcur + zeroes gsumAll)
__global__ void k_wpack_all(
        const float* __restrict__ w00, const float* __restrict__ w01, const float* __restrict__ w02,
        const float* __restrict__ w10, const float* __restrict__ w11, const float* __restrict__ w12,
        const float* __restrict__ w20, const float* __restrict__ w21, const float* __restrict__ w22,
        ushort* __restrict__ WP0, ushort* __restrict__ WP1, ushort* __restrict__ WP2,
        int* __restrict__ gcur, float* __restrict__ gsumAll) {
    int l = blockIdx.z, p = blockIdx.y;
    int kt = blockIdx.x >> 2, ct = blockIdx.x & 3;
    int lane = threadIdx.x;  // 0..63
    if (l == 0 && p == 0 && blockIdx.x == 0) {
        for (int i = lane; i < NBUCK; i += 64) gcur[i] = i * BCAP;
    }
    if (l == 0 && p == 1 && blockIdx.x == 0) {
        for (int i = lane; i < 3 * 2 * CAT; i += 64) gsumAll[i] = 0.f;
    }
    int KT = (l == 0) ? 4 : 6;
    if (kt >= KT) return;
    const float* W;
    if (l == 0) W = (p == 0) ? w00 : ((p == 1) ? w01 : w02);
    else if (l == 1) W = (p == 0) ? w10 : ((p == 1) ? w11 : w12);
    else W = (p == 0) ? w20 : ((p == 1) ? w21 : w22);
    ushort* WP = (l == 0) ? WP0 : ((l == 1) ? WP1 : WP2);
    int k0 = kt * 32 + (lane >> 4) * 8;
    int c = ct * 16 + (lane & 15);
    ushort* dst = WP + (((size_t)(p * KT + kt) * 4 + ct) << 9) + (lane << 3);
    ushort o[8];
#pragma unroll
    for (int j = 0; j < 8; ++j) {
        int kl = k0 + j;
        float v = 0.f;
        if (c < 60) {
            if (l == 0) {
                if (kl < FIN0) v = W[(size_t)kl * 60 + c];
            } else {
                int rgn = kl >> 6, cc = kl & 63;
                if (cc < 60) v = W[(size_t)(rgn * 60 + cc) * 60 + c];
            }
        }
        o[j] = f2bf(v);
    }
    *(ushort4*)dst = make_ushort4(o[0], o[1], o[2], o[3]);
    *(ushort4*)(dst + 4) = make_ushort4(o[4], o[5], o[6], o[7]);
}

// ---------------- CSR build: bucketed, write-combined, 4B packed entries ----
// entry: bits 0-15 = src (N < 65536), bits 16-23 = dst & 255
__global__ __launch_bounds__(256) void k_bin(const int* __restrict__ src,
                                             const int* __restrict__ dst,
                                             int* __restrict__ gcur,
                                             uint* __restrict__ ebuf, int e) {
    __shared__ int cnt[NBUCK];
    __shared__ int base[NBUCK];
    int t = threadIdx.x;
    for (int c0 = blockIdx.x * 2048; c0 < e; c0 += gridDim.x * 2048) {
        if (t < NBUCK) cnt[t] = 0;
        __syncthreads();
        uint pe[8]; int rk[8], bk[8], ok[8];
#pragma unroll
        for (int j = 0; j < 8; ++j) {
            int i = c0 + j * 256 + t;
            ok[j] = i < e;
            if (ok[j]) {
                int sv = src[i], dv = dst[i];
                pe[j] = (uint)(sv & 0xFFFF) | ((uint)(dv & 255) << 16);
                bk[j] = dv >> 8;
                rk[j] = atomicAdd(&cnt[bk[j]], 1);
            }
        }
        __syncthreads();
        if (t < NBUCK && cnt[t] > 0) base[t] = atomicAdd(&gcur[t], cnt[t]);
        __syncthreads();
#pragma unroll
        for (int j = 0; j < 8; ++j) {
            if (ok[j]) ebuf[base[bk[j]] + rk[j]] = pe[j];
        }
        __syncthreads();
    }
}

// one block per bucket: inline global prefix scan (196 counts), then exact CSR
__global__ __launch_bounds__(256) void k_bucket_csr(
        const int* __restrict__ gcur, const uint* __restrict__ ebuf,
        int* __restrict__ row_ptr, float* __restrict__ dinv,
        ushort* __restrict__ ssrc, int n) {
    __shared__ int sc[256];
    __shared__ int ncnt[256];
    __shared__ int loff[256];
    int b = blockIdx.x, t = threadIdx.x;
    int cbt = (t < NBUCK) ? (gcur[t] - t * BCAP) : 0;
    sc[t] = cbt;
    __syncthreads();
    for (int off = 1; off < 256; off <<= 1) {
        int v = (t >= off) ? sc[t - off] : 0;
        __syncthreads();
        sc[t] += v;
        __syncthreads();
    }
    int gbase = (b == 0) ? 0 : sc[b - 1];
    int cnt = sc[b] - gbase;
    if (b == 0 && t == 0) row_ptr[NN] = NE;
    const uint* ee = ebuf + (size_t)b * BCAP;
    ncnt[t] = 0;
    __syncthreads();
    for (int i = t; i < cnt; i += 256) atomicAdd(&ncnt[(ee[i] >> 16) & 255], 1);
    __syncthreads();
    int c = ncnt[t];
    loff[t] = c;
    __syncthreads();
    for (int off = 1; off < 256; off <<= 1) {
        int v = (t >= off) ? loff[t - off] : 0;
        __syncthreads();
        loff[t] += v;
        __syncthreads();
    }
    int excl = loff[t] - c;
    int node = b * 256 + t;
    if (node < n) {
        row_ptr[node] = gbase + excl;
        dinv[node] = rsqrtf((float)(c + 1));  // +1 self loop
    }
    __syncthreads();
    ncnt[t] = excl;  // reuse as cursor
    __syncthreads();
    for (int i = t; i < cnt; i += 256) {
        uint pe = ee[i];
        int pos = atomicAdd(&ncnt[(pe >> 16) & 255], 1);
        ssrc[gbase + pos] = (ushort)(pe & 0xFFFF);
    }
}

// ---------------- MFMA GEMM, 3 powers per block.
template <int KT, int MODE>
__global__ __launch_bounds__(256) void k_gemm_mfma(
        const float* __restrict__ Xf,
        const ushort* __restrict__ B0q, const ushort* __restrict__ B1q,
        const ushort* __restrict__ B2q,
        const float* __restrict__ gsum, const float* __restrict__ gsum2,
        const float* __restrict__ bng, const float* __restrict__ bnb,
        const ushort* __restrict__ WP,
        const float* __restrict__ b0, const float* __restrict__ dinv,
        ushort* __restrict__ Y0, ushort* __restrict__ Y12, int n) {
    __shared__ float ssc[200], ssh[200];
    const int t = threadIdx.x;
    if (MODE == 1) {
        if (t < 192) {
            int rgn = t >> 6, cc = t & 63;
            float sc = 0.f, sh = 0.f;
            if (cc < 60) {
                int c = rgn * 60 + cc;
                float mu = gsum[c] / (float)n;
                float var = gsum2[c] / (float)n - mu * mu;
                sc = rsqrtf(var + BN_EPS) * bng[c];
                sh = bnb[c] - mu * sc;
            }
            ssc[t] = sc; ssh[t] = sh;
        }
        __syncthreads();
    }
    const int wv = t >> 6;
    const int lane = t & 63;
    const int l15 = lane & 15;
    const int lhi = lane >> 4;
    const int nb = blockIdx.x * 64 + wv * 16;

    f32x4 acc[3][4];
#pragma unroll
    for (int p = 0; p < 3; ++p)
#pragma unroll
        for (int ct = 0; ct < 4; ++ct) acc[p][ct] = (f32x4){0.f, 0.f, 0.f, 0.f};

    const int arow = nb + l15;
    const int arowc = (arow < n) ? arow : 0;
    const ushort* wpL = WP + (lane << 3);

#pragma unroll
    for (int kt = 0; kt < KT; ++kt) {
        short8 a;
        if (MODE == 0) {
            const float* xr = Xf + (size_t)arowc * (KT * 32) + kt * 32 + lhi * 8;
            float4 v0 = *(const float4*)xr;
            float4 v1 = *(const float4*)(xr + 4);
            a[0] = (short)f2bf(v0.x); a[1] = (short)f2bf(v0.y);
            a[2] = (short)f2bf(v0.z); a[3] = (short)f2bf(v0.w);
            a[4] = (short)f2bf(v1.x); a[5] = (short)f2bf(v1.y);
            a[6] = (short)f2bf(v1.z); a[7] = (short)f2bf(v1.w);
        } else {
            const ushort* base = (kt < 2) ? B0q : ((kt < 4) ? B1q : B2q);
            const ushort* ar = base + (size_t)arowc * 64 + (kt & 1) * 32 + lhi * 8;
            uint4 raw = *(const uint4*)ar;
            int kb = kt * 32 + lhi * 8;
            float4 sc0 = *(const float4*)&ssc[kb];
            float4 sc1 = *(const float4*)&ssc[kb + 4];
            float4 sh0 = *(const float4*)&ssh[kb];
            float4 sh1 = *(const float4*)&ssh[kb + 4];
            a[0] = (short)f2bf(bf_lo(raw.x) * sc0.x + sh0.x);
            a[1] = (short)f2bf(bf_hi(raw.x) * sc0.y + sh0.y);
            a[2] = (short)f2bf(bf_lo(raw.y) * sc0.z + sh0.z);
            a[3] = (short)f2bf(bf_hi(raw.y) * sc0.w + sh0.w);
            a[4] = (short)f2bf(bf_lo(raw.z) * sc1.x + sh1.x);
            a[5] = (short)f2bf(bf_hi(raw.z) * sc1.y + sh1.y);
            a[6] = (short)f2bf(bf_lo(raw.w) * sc1.z + sh1.z);
            a[7] = (short)f2bf(bf_hi(raw.w) * sc1.w + sh1.w);
        }
#pragma unroll
        for (int p = 0; p < 3; ++p)
#pragma unroll
            for (int ct = 0; ct < 4; ++ct) {
                short8 b = *(const short8*)(wpL + (((size_t)(p * KT + kt) * 4 + ct) << 9));
                acc[p][ct] = __builtin_amdgcn_mfma_f32_16x16x32_bf16(a, b, acc[p][ct], 0, 0, 0);
            }
    }

    // C/D layout: col = lane&15, row = (lane>>4)*4 + reg
    float dv[4];
#pragma unroll
    for (int j = 0; j < 4; ++j) {
        int node = nb + lhi * 4 + j;
        dv[j] = (node < n) ? dinv[node] : 0.f;
    }
#pragma unroll
    for (int ct = 0; ct < 4; ++ct) {
        int col = ct * 16 + l15;
        if (col >= 60) continue;
        float bias = b0[col];
#pragma unroll
        for (int j = 0; j < 4; ++j) {
            int node = nb + lhi * 4 + j;
            if (node >= n) continue;
            Y0[(size_t)node * 64 + col] = f2bf(acc[0][ct][j] + bias);
            uint pk = ((uint)f2bf(dv[j] * acc[2][ct][j]) << 16) |
                      (uint)f2bf(dv[j] * acc[1][ct][j]);
            *(uint*)(Y12 + (size_t)node * 128 + 2 * col) = pk;
        }
    }
}

// ---------------- propA: 1 node/wave, LDS-staged indices, 16-deep gathers
__global__ __launch_bounds__(256) void k_propA(
        const ushort* __restrict__ Y12, ushort* __restrict__ Z1, ushort* __restrict__ ZQ,
        const float* __restrict__ b1,
        const float* __restrict__ dinv, const int* __restrict__ rp,
        const ushort* __restrict__ es, int n) {
    __shared__ ushort sidx[4][STG];
    int sub = threadIdx.x >> 6;
    int lane = threadIdx.x & 63;
    int node = blockIdx.x * 4 + sub;
    if (node >= n) return;
    int e0 = rp[node], e1 = rp[node + 1];
    int deg = e1 - e0;
    int stg = (deg < STG) ? deg : STG;
    for (int i = lane; i < stg; i += 64) sidx[sub][i] = es[e0 + i];
    // same-wave LDS write->read: compiler inserts lgkmcnt wait, no barrier needed
    if (lane >= 60) return;
    uint sv = *(const uint*)(Y12 + (size_t)node * 128 + 2 * lane);
    float a1 = bf_lo(sv);
    float a2 = bf_hi(sv);
    int e = 0;
    for (; e + 15 < stg; e += 16) {
        uint v[16];
#pragma unroll
        for (int j = 0; j < 16; ++j) {
            int s = sidx[sub][e + j];
            v[j] = *(const uint*)(Y12 + (size_t)s * 128 + 2 * lane);
        }
#pragma unroll
        for (int j = 0; j < 16; ++j) { a1 += bf_lo(v[j]); a2 += bf_hi(v[j]); }
    }
    for (; e + 3 < stg; e += 4) {
        uint v[4];
#pragma unroll
        for (int j = 0; j < 4; ++j) {
            int s = sidx[sub][e + j];
            v[j] = *(const uint*)(Y12 + (size_t)s * 128 + 2 * lane);
        }
#pragma unroll
        for (int j = 0; j < 4; ++j) { a1 += bf_lo(v[j]); a2 += bf_hi(v[j]); }
    }
    for (; e < stg; ++e) {
        uint v = *(const uint*)(Y12 + (size_t)sidx[sub][e] * 128 + 2 * lane);
        a1 += bf_lo(v);
        a2 += bf_hi(v);
    }
    for (int ee = e0 + stg; ee < e1; ++ee) {  // overflow tail (rare)
        uint v = *(const uint*)(Y12 + (size_t)es[ee] * 128 + 2 * lane);
        a1 += bf_lo(v);
        a2 += bf_hi(v);
    }
    float di = dinv[node];
    Z1[(size_t)node * 64 + lane] = f2bf(di * a1 + b1[lane]);
    ZQ[(size_t)node * 64 + lane] = f2bf(di * di * a2);
}

// ---------------- propB: 1 node/wave over ZQ (s64) -> Q2 bf16 s64 (+b2)
__global__ __launch_bounds__(256) void k_propB(
        const ushort* __restrict__ ZQ, ushort* __restrict__ Q2,
        const float* __restrict__ b2,
        const float* __restrict__ dinv, const int* __restrict__ rp,
        const ushort* __restrict__ es, int n) {
    __shared__ ushort sidx[4][STG];
    int sub = threadIdx.x >> 6;
    int lane = threadIdx.x & 63;
    int node = blockIdx.x * 4 + sub;
    if (node >= n) return;
    int e0 = rp[node], e1 = rp[node + 1];
    int deg = e1 - e0;
    int stg = (deg < STG) ? deg : STG;
    for (int i = lane; i < stg; i += 64) sidx[sub][i] = es[e0 + i];
    if (lane >= 60) return;
    float acc = bf2f(ZQ[(size_t)node * 64 + lane]);
    int e = 0;
    for (; e + 15 < stg; e += 16) {
        ushort v[16];
#pragma unroll
        for (int j = 0; j < 16; ++j) {
            int s = sidx[sub][e + j];
            v[j] = ZQ[(size_t)s * 64 + lane];
        }
#pragma unroll
        for (int j = 0; j < 16; ++j) acc += bf2f(v[j]);
    }
    for (; e + 3 < stg; e += 4) {
        ushort v[4];
#pragma unroll
        for (int j = 0; j < 4; ++j) {
            int s = sidx[sub][e + j];
            v[j] = ZQ[(size_t)s * 64 + lane];
        }
#pragma unroll
        for (int j = 0; j < 4; ++j) acc += bf2f(v[j]);
    }
    for (; e < stg; ++e) acc += bf2f(ZQ[(size_t)sidx[sub][e] * 64 + lane]);
    for (int ee = e0 + stg; ee < e1; ++ee) acc += bf2f(ZQ[(size_t)es[ee] * 64 + lane]);
    Q2[(size_t)node * 64 + lane] = f2bf(dinv[node] * acc + b2[lane]);
}

// ---------------- BN stats: coalesced uint4 reads, shfl+LDS reduce
__global__ __launch_bounds__(256) void k_bnstats(
        const ushort* __restrict__ Y0, const ushort* __restrict__ Z1,
        const ushort* __restrict__ Q2,
        float* __restrict__ gsum, float* __restrict__ gsum2, int n) {
    int rgn = blockIdx.y;
    const ushort* __restrict__ src = (rgn == 0) ? Y0 : ((rgn == 1) ? Z1 : Q2);
    int t = threadIdx.x;
    int c8 = (t & 7) * 8;
    int rsub = t >> 3;
    float s1[8], s2[8];
#pragma unroll
    for (int j = 0; j < 8; ++j) { s1[j] = 0.f; s2[j] = 0.f; }
    for (int r = blockIdx.x * 32 + rsub; r < n; r += gridDim.x * 32) {
        uint4 v = *(const uint4*)(src + (size_t)r * 64 + c8);
        float f;
        f = bf_lo(v.x); s1[0] += f; s2[0] += f * f;
        f = bf_hi(v.x); s1[1] += f; s2[1] += f * f;
        f = bf_lo(v.y); s1[2] += f; s2[2] += f * f;
        f = bf_hi(v.y); s1[3] += f; s2[3] += f * f;
        f = bf_lo(v.z); s1[4] += f; s2[4] += f * f;
        f = bf_hi(v.z); s1[5] += f; s2[5] += f * f;
        f = bf_lo(v.w); s1[6] += f; s2[6] += f * f;
        f = bf_hi(v.w); s1[7] += f; s2[7] += f * f;
    }
#pragma unroll
    for (int m = 8; m < 64; m <<= 1) {
#pragma unroll
        for (int j = 0; j < 8; ++j) {
            s1[j] += __shfl_xor(s1[j], m);
            s2[j] += __shfl_xor(s2[j], m);
        }
    }
    __shared__ float ls1[4][64], ls2[4][64];
    int wv = t >> 6, lane = t & 63;
    if (lane < 8) {
#pragma unroll
        for (int j = 0; j < 8; ++j) {
            ls1[wv][lane * 8 + j] = s1[j];
            ls2[wv][lane * 8 + j] = s2[j];
        }
    }
    __syncthreads();
    if (t < 60) {
        float a1 = ls1[0][t] + ls1[1][t] + ls1[2][t] + ls1[3][t];
        float a2 = ls2[0][t] + ls2[1][t] + ls2[2][t] + ls2[3][t];
        atomicAdd(&gsum[rgn * 60 + t], a1);
        atomicAdd(&gsum2[rgn * 60 + t], a2);
    }
}

// ---------------- final linear with fused BN (layer 3): out = BN(h) @ w + b
__global__ __launch_bounds__(256) void k_final_fused(
        const ushort* __restrict__ Y0, const ushort* __restrict__ Z1,
        const ushort* __restrict__ Q2,
        const float* __restrict__ gsum, const float* __restrict__ gsum2,
        const float* __restrict__ g, const float* __restrict__ bb,
        const float* __restrict__ w, const float* __restrict__ wb,
        float* __restrict__ out, int n) {
    __shared__ float sw[CAT * NCLS];
    __shared__ float ssc[CAT], ssh[CAT];
    __shared__ float sb[NCLS];
    int t = threadIdx.x;
    for (int i = t; i < CAT * NCLS; i += 256) sw[i] = w[i];
    if (t < CAT) {
        float mu = gsum[t] / (float)n;
        float var = gsum2[t] / (float)n - mu * mu;
        float sc = rsqrtf(var + BN_EPS) * g[t];
        ssc[t] = sc;
        ssh[t] = bb[t] - mu * sc;
    }
    if (t < NCLS) sb[t] = wb[t];
    __syncthreads();
    int node = blockIdx.x * 256 + t;
    if (node >= n) return;
    float acc[NCLS];
#pragma unroll
    for (int j = 0; j < NCLS; ++j) acc[j] = sb[j];
    const ushort* bufs[3] = {Y0, Z1, Q2};
#pragma unroll
    for (int rgn = 0; rgn < 3; ++rgn) {
        const ushort* sp = bufs[rgn] + (size_t)node * 64;
        int cb = rgn * 60;
#pragma unroll 6
        for (int k2 = 0; k2 < 30; ++k2) {
            uint u = *(const uint*)(sp + 2 * k2);
            int c = cb + 2 * k2;
            float f0 = bf_lo(u) * ssc[c] + ssh[c];
            float f1 = bf_hi(u) * ssc[c + 1] + ssh[c + 1];
#pragma unroll
            for (int j = 0; j < NCLS; ++j)
                acc[j] += f0 * sw[c * NCLS + j] + f1 * sw[(c + 1) * NCLS + j];
        }
    }
#pragma unroll
    for (int j = 0; j < NCLS; ++j) out[(size_t)node * NCLS + j] = acc[j];
}

extern "C" void kernel_launch(void* const* d_in, const int* in_sizes, int n_in,
                              void* d_out, int out_size, void* d_ws, size_t ws_size,
                              hipStream_t stream) {
    const float* x = (const float*)d_in[0];
    const int* ei = (const int*)d_in[1];
    const int* esrc = ei;
    const int* edst = ei + NE;

    const float* c_w[3][3];
    const float* c_b[3][3];
    for (int p = 0; p < 3; ++p)
        for (int l = 0; l < 3; ++l) {
            c_w[l][p] = (const float*)d_in[2 + p * 6 + l * 2];
            c_b[l][p] = (const float*)d_in[3 + p * 6 + l * 2];
        }
    const float* bn_g[3] = {(const float*)d_in[20], (const float*)d_in[22], (const float*)d_in[24]};
    const float* bn_b[3] = {(const float*)d_in[21], (const float*)d_in[23], (const float*)d_in[25]};
    const float* lw = (const float*)d_in[26];
    const float* lb = (const float*)d_in[27];
    float* out = (float*)d_out;

    char* wp = (char*)d_ws;
    auto alloc = [&](size_t bytes) {
        char* p = wp;
        wp += (bytes + 255) & ~(size_t)255;
        return p;
    };
    int* gcur = (int*)alloc((size_t)NBUCK * 4);
    uint* ebuf = (uint*)alloc((size_t)NBUCK * BCAP * 4);
    int* row_ptr = (int*)alloc((size_t)(NN + 1) * 4);
    ushort* ssrc = (ushort*)alloc((size_t)NE * 2);
    float* dinv = (float*)alloc((size_t)NN * 4);
    float* gsumAll = (float*)alloc((size_t)3 * 2 * CAT * 4);  // [layer][sum|sum2]
    ushort* Y0 = (ushort*)alloc((size_t)NN * 64 * 2);
    ushort* Y12 = (ushort*)alloc((size_t)NN * 128 * 2);
    ushort* Z1 = (ushort*)alloc((size_t)NN * 64 * 2);
    ushort* ZQ = (ushort*)alloc((size_t)NN * 64 * 2);
    ushort* Q2 = (ushort*)alloc((size_t)NN * 64 * 2);
    ushort* WP1 = (ushort*)alloc((size_t)3 * 4 * 4 * 512 * 2);
    ushort* WP2 = (ushort*)alloc((size_t)3 * 6 * 4 * 512 * 2);
    ushort* WP3 = (ushort*)alloc((size_t)3 * 6 * 4 * 512 * 2);

    auto gs = [&](int l) { return gsumAll + (size_t)l * 2 * CAT; };
    auto gs2 = [&](int l) { return gsumAll + (size_t)l * 2 * CAT + CAT; };

    // ---- weight packs + gcur init + gsum zero (one launch) ----
    k_wpack_all<<<dim3(24, 3, 3), 64, 0, stream>>>(
        c_w[0][0], c_w[0][1], c_w[0][2],
        c_w[1][0], c_w[1][1], c_w[1][2],
        c_w[2][0], c_w[2][1], c_w[2][2],
        WP1, WP2, WP3, gcur, gsumAll);

    // ---- CSR build (write-combined bucketed sort) ----
    k_bin<<<391, 256, 0, stream>>>(esrc, edst, gcur, ebuf, NE);
    k_bucket_csr<<<NBUCK, 256, 0, stream>>>(gcur, ebuf, row_ptr, dinv, ssrc, NN);

    const int gemm_gx = (NN + 63) / 64;
    const int prop_gx = (NN + 3) / 4;

    for (int l = 0; l < 3; ++l) {
        if (l == 0) {
            k_gemm_mfma<4, 0><<<gemm_gx, 256, 0, stream>>>(
                x, nullptr, nullptr, nullptr, nullptr, nullptr, nullptr, nullptr,
                WP1, c_b[0][0], dinv, Y0, Y12, NN);
        } else {
            const ushort* WPl = (l == 1) ? WP2 : WP3;
            k_gemm_mfma<6, 1><<<gemm_gx, 256, 0, stream>>>(
                nullptr, Y0, Z1, Q2, gs(l - 1), gs2(l - 1), bn_g[l - 1], bn_b[l - 1],
                WPl, c_b[l][0], dinv, Y0, Y12, NN);
        }
        k_propA<<<prop_gx, 256, 0, stream>>>(Y12, Z1, ZQ, c_b[l][1], dinv, row_ptr, ssrc, NN);
        k_propB<<<prop_gx, 256, 0, stream>>>(ZQ, Q2, c_b[l][2], dinv, row_ptr, ssrc, NN);
        k_bnstats<<<dim3(256, 3), 256, 0, stream>>>(Y0, Z1, Q2, gs(l), gs2(l), NN);
    }

    k_final_fused<<<(NN + 255) / 256, 256, 0, stream>>>(
        Y0, Z1, Q2, gs(2), gs2(2), bn_g[2], bn_b[2], lw, lb, out, NN);
}